// Round 4
// baseline (681.370 us; speedup 1.0000x reference)
//
#include <hip/hip_runtime.h>
#include <hip/hip_bf16.h>

typedef __hip_bfloat16 bf16;
typedef __attribute__((ext_vector_type(8))) short short8;
typedef __attribute__((ext_vector_type(4))) float f32x4;

#define DD    172      // D
#define EE    172      // E
#define QIN   272      // D+T
#define KK    20
#define HH    2
#define DHH   86
#define N0C   512
#define N1C   10240
#define M1    204800   // N1*K rows
#define M0    10240    // N0*K rows

// GEMM geometry
#define BM   128
#define BN   192
#define BK   64
#define KP   448       // kv_in padded K (444 -> 448)
#define QS   320       // qin padded K (272 -> 320)
#define F1S  384       // f1in padded K (344 -> 384)
#define HS   192       // h padded K (172 -> 192)
#define KVS  384       // kv row stride (k|v = 344, padded)
#define NPADR 384      // wkvT rows per layer

#define GLOAD(src, dst) __builtin_amdgcn_global_load_lds( \
    (const __attribute__((address_space(1))) unsigned int*)(src), \
    (__attribute__((address_space(3))) unsigned int*)(dst), 16, 0, 0)

__device__ __forceinline__ float bfu2f(unsigned short u) {
    return __uint_as_float(((unsigned)u) << 16);
}

// ---------------- mask dtype probe -------------------------------------
__global__ void probe_mask_kernel(const unsigned* __restrict__ m, int n_ints,
                                  int* __restrict__ mode_out) {
    __shared__ int c_other, c_float;
    if (threadIdx.x == 0) { c_other = 0; c_float = 0; }
    __syncthreads();
    int lo = 0, lf = 0;
    for (int i = threadIdx.x; i < n_ints; i += blockDim.x) {
        unsigned v = m[i];
        if (v == 0x3F800000u) lf++;
        else if (v > 1u) lo++;
    }
    if (lo) atomicAdd(&c_other, lo);
    if (lf) atomicAdd(&c_float, lf);
    __syncthreads();
    if (threadIdx.x == 0) {
        int mode = 0;
        if (c_float > 0) mode = 2;
        else if (c_other > 0) mode = 1;
        *mode_out = mode;
    }
}

__device__ __forceinline__ bool get_mask(const void* m, int mode, int idx) {
    if (mode == 1) return ((const unsigned char*)m)[idx] != 0;
    if (mode == 2) return ((const float*)m)[idx] != 0.0f;
    return ((const int*)m)[idx] != 0;
}

// ---------------- weight prep: wkvT[l][n][k] bf16 + fused bias(384) -----
__global__ void prep_wkvT_kernel(const float* __restrict__ wk, const float* __restrict__ wv,
                                 const float* __restrict__ bk, const float* __restrict__ bv,
                                 bf16* __restrict__ wkvT, float* __restrict__ biaskv) {
    size_t i = (size_t)blockIdx.x * blockDim.x + threadIdx.x;
    size_t tot = (size_t)2 * NPADR * KP;
    if (i >= tot) return;
    int l = (int)(i / ((size_t)NPADR * KP));
    int rem = (int)(i % ((size_t)NPADR * KP));
    int k = rem / NPADR;
    int n = rem % NPADR;
    float v = 0.f;
    if (k < 444) {
        if (n < DD)          v = wk[((size_t)l * 444 + k) * DD + n];
        else if (n < 2 * DD) v = wv[((size_t)l * 444 + k) * DD + (n - DD)];
    }
    wkvT[((size_t)l * NPADR + n) * KP + k] = __float2bfloat16(v);
    if (i < 2 * 384) {
        int nn = (int)(i % 384), ll = (int)(i / 384);
        biaskv[i] = nn < DD ? bk[ll * DD + nn] : (nn < 2 * DD ? bv[ll * DD + nn - DD] : 0.f);
    }
}

// ---------------- generic weight transpose: W[K][172] -> dstT[192][KPdst]
__global__ void prep_wT_kernel(const float* __restrict__ W, const float* __restrict__ b,
                               int K, int KPdst,
                               bf16* __restrict__ dstT, float* __restrict__ biasdst) {
    int i = blockIdx.x * blockDim.x + threadIdx.x;
    int tot = 192 * KPdst;
    if (i < tot) {
        int n = i / KPdst, k = i % KPdst;
        float v = (n < DD && k < K) ? W[(size_t)k * DD + n] : 0.f;
        dstT[(size_t)n * KPdst + k] = __float2bfloat16(v);
    }
    if (i < 192) biasdst[i] = (i < DD) ? b[i] : 0.f;
}

// ---------------- kv_in staging: [nbr_feat | edge | cos(dt*w+b) | 0pad] --
// 16B-vectorized: lane u < 56 handles cols [8u, 8u+8)
__global__ __launch_bounds__(256) void stage_kvin_kernel(
    const float* __restrict__ sf, const int* __restrict__ nbrs,
    const float* __restrict__ edge, const float* __restrict__ times,
    const float* __restrict__ nbrt,
    const void* __restrict__ mask, const int* __restrict__ mode_p,
    const float* __restrict__ time_w, const float* __restrict__ time_b,
    const float* __restrict__ zbuf, const int* __restrict__ g2l, int use_z,
    int row0, bf16* __restrict__ out) {
    int wave = threadIdx.x >> 6, lane = threadIdx.x & 63;
    int lrow = blockIdx.x * 4 + wave;
    int row = row0 + lrow;
    int mode = *mode_p;
    int g = nbrs[row];
    bool mk = get_mask(mask, mode, row);
    float dt = mk ? (times[row / KK] - nbrt[row]) : 0.f;
    const float* src = (use_z && mk) ? (zbuf + (size_t)g2l[g] * DD)
                                     : (sf + (size_t)g * DD);
    const float* erow = edge + (size_t)row * EE;
    bf16* orow = out + (size_t)lrow * KP;
    if (lane < 56) {
        int c0 = lane * 8;
        union { bf16 h[8]; short8 s; } u;
#pragma unroll
        for (int e = 0; e < 8; ++e) {
            int col = c0 + e;
            float v;
            if (col < DD)           v = src[col];
            else if (col < DD + EE) v = erow[col - DD];
            else if (col < 444)     { int t = col - DD - EE; v = cosf(dt * time_w[t] + time_b[t]); }
            else                    v = 0.f;
            u.h[e] = __float2bfloat16(v);
        }
        *(short8*)(orow + c0) = u.s;
    }
}

// ---------------- q_in staging: [feat | cos(time_b) | 0pad] -------------
__global__ __launch_bounds__(256) void stage_qin_kernel(
    const float* __restrict__ sf, const int* __restrict__ idx,
    const float* __restrict__ time_b, bf16* __restrict__ out) {
    int wave = threadIdx.x >> 6, lane = threadIdx.x & 63;
    int row = blockIdx.x * 4 + wave;
    const float* src = sf + (size_t)idx[row] * DD;
    bf16* orow = out + (size_t)row * QS;
    if (lane < 40) {
        int c0 = lane * 8;
        union { bf16 h[8]; short8 s; } u;
#pragma unroll
        for (int e = 0; e < 8; ++e) {
            int col = c0 + e;
            float v;
            if (col < DD)       v = src[col];
            else if (col < QIN) v = cosf(time_b[col - DD]);
            else                v = 0.f;
            u.h[e] = __float2bfloat16(v);
        }
        *(short8*)(orow + c0) = u.s;
    }
}

// ---------------- 192-col MFMA GEMM -------------------------------------
// 128x192 tile, 4 waves in 2M x 2N, per wave 64x96 (acc 4x6 frags).
// OMODE 0: bf16 dense out (stride ostride, 16B-aligned), LDS-repacked float4 stores.
// OMODE 2: fp32 scatter rows via g2l[idx[row]], cols < 172 (scalar stores).
template<int KP_, int NT, bool RELU, int OMODE>
__global__ __launch_bounds__(256) void gemm192_kernel(
    const bf16* __restrict__ A, const bf16* __restrict__ BT,
    const float* __restrict__ bias, void* __restrict__ outp, int ostride,
    const int* __restrict__ idx, const int* __restrict__ g2l, int Mtiles) {
    __shared__ __align__(16) char smem[51200];   // As 16K | Bs 24K ; reused as Cs[128][200]
    int tid = threadIdx.x;
    int lane = tid & 63, wave = tid >> 6;
    int ml = lane & 15, kg = lane >> 4;
    int wm = wave >> 1, wn = wave & 1;
    int bid = blockIdx.x;
    int mt = (NT == 2) ? (bid % Mtiles) : bid;
    int nt = (NT == 2) ? (bid / Mtiles) : 0;
    int m0 = mt * BM, n0 = nt * BN;

    f32x4 acc[4][6];
#pragma unroll
    for (int mg = 0; mg < 4; ++mg)
#pragma unroll
        for (int fn = 0; fn < 6; ++fn)
            acc[mg][fn] = (f32x4){0.f, 0.f, 0.f, 0.f};

    for (int kk = 0; kk < KP_; kk += BK) {
        // stage A: 128 rows x 8 slots = 1024 chunks; linear LDS dest, pre-swizzled src
#pragma unroll
        for (int it = 0; it < 4; ++it) {
            int c = it * 256 + tid;
            int row = c >> 3, slot = c & 7;
            int sslot = slot ^ (row & 7);
            const bf16* src = A + (size_t)(m0 + row) * KP_ + kk + sslot * 8;
            GLOAD(src, smem + (size_t)(it * 256 + wave * 64) * 16);
        }
        // stage B: 192 rows x 8 slots = 1536 chunks
#pragma unroll
        for (int it = 0; it < 6; ++it) {
            int c = it * 256 + tid;
            int row = c >> 3, slot = c & 7;
            int sslot = slot ^ (row & 7);
            const bf16* src = BT + (size_t)(n0 + row) * KP_ + kk + sslot * 8;
            GLOAD(src, smem + 16384 + (size_t)(it * 256 + wave * 64) * 16);
        }
        __syncthreads();
#pragma unroll
        for (int half = 0; half < 2; ++half) {
            int kc = kg + half * 4;
            short8 a[4], b[6];
#pragma unroll
            for (int mg = 0; mg < 4; ++mg) {
                int r = wm * 64 + mg * 16 + ml;
                a[mg] = *(const short8*)(smem + r * 128 + ((kc ^ (r & 7)) << 4));
            }
#pragma unroll
            for (int fn = 0; fn < 6; ++fn) {
                int r = wn * 96 + fn * 16 + ml;
                b[fn] = *(const short8*)(smem + 16384 + r * 128 + ((kc ^ (r & 7)) << 4));
            }
#pragma unroll
            for (int mg = 0; mg < 4; ++mg)
#pragma unroll
                for (int fn = 0; fn < 6; ++fn)
                    acc[mg][fn] = __builtin_amdgcn_mfma_f32_16x16x32_bf16(a[mg], b[fn], acc[mg][fn], 0, 0, 0);
        }
        __syncthreads();
    }

    if (OMODE == 0) {
        // repack: acc -> Cs[128][200] bf16 (bias+relu fused), then float4 stores
        bf16* Cs = (bf16*)smem;
#pragma unroll
        for (int fn = 0; fn < 6; ++fn) {
            int col = wn * 96 + fn * 16 + ml;
            float bb = bias[n0 + col];
#pragma unroll
            for (int mg = 0; mg < 4; ++mg)
#pragma unroll
                for (int r4 = 0; r4 < 4; ++r4) {
                    int row = wm * 64 + mg * 16 + kg * 4 + r4;
                    float v = acc[mg][fn][r4] + bb;
                    if (RELU) v = fmaxf(v, 0.f);
                    Cs[row * 200 + col] = __float2bfloat16(v);
                }
        }
        __syncthreads();
        char* ob = (char*)outp;
        for (int c = tid; c < 128 * 24; c += 256) {
            int row = c / 24, u = c % 24;
            float4 v = *(const float4*)(smem + row * 400 + u * 16);
            *(float4*)(ob + ((size_t)(m0 + row) * ostride + n0) * 2 + u * 16) = v;
        }
    } else {
        // fp32 scatter (FFN2 -> z)
#pragma unroll
        for (int fn = 0; fn < 6; ++fn) {
            int col = wn * 96 + fn * 16 + ml;
            if (col < DD) {
                float bb = bias[col];
#pragma unroll
                for (int mg = 0; mg < 4; ++mg)
#pragma unroll
                    for (int r4 = 0; r4 < 4; ++r4) {
                        int row = m0 + wm * 64 + mg * 16 + kg * 4 + r4;
                        float v = acc[mg][fn][r4] + bb;
                        if (RELU) v = fmaxf(v, 0.f);
                        int zr = g2l[idx[row]];
                        ((float*)outp)[(size_t)zr * DD + col] = v;
                    }
            }
        }
    }
}

// ---------------- attention over K=20 neighbors -------------------------
// kv row stride 384; q bf16 stride 192. Writes o + gathered nf into f1in[row][F1S].
#define ASTR 392
__global__ __launch_bounds__(64) void attn_kernel(
    const bf16* __restrict__ q, const bf16* __restrict__ kv,
    const void* __restrict__ mask, const int* __restrict__ mode_p,
    const float* __restrict__ sf, const int* __restrict__ idx,
    bf16* __restrict__ f1out) {
    int node = blockIdx.x;
    int lane = threadIdx.x;
    __shared__ unsigned short kvls[KK][ASTR];
    __shared__ float qs[DD];
    __shared__ float sc[HH][KK];
    __shared__ float aw[HH][KK];
    int mode = *mode_p;
    const unsigned short* kvg = (const unsigned short*)(kv + (size_t)node * KK * KVS);
    for (int c = lane; c < 960; c += 64) {          // 20*384/8 chunks, contiguous
        int r = c / 48, cc = c % 48;
        *(short8*)&kvls[r][cc * 8] = *(const short8*)(kvg + (size_t)c * 8);
    }
    const unsigned short* qrow = (const unsigned short*)q + (size_t)node * 192;
    for (int i = lane; i < DD; i += 64) qs[i] = bfu2f(qrow[i]);
    __syncthreads();
    if (lane < HH * KK) {
        int h = lane / KK, kx = lane % KK;
        bool mk = get_mask(mask, mode, node * KK + kx);
        float s = 0.f;
        const unsigned short* kr = &kvls[kx][h * DHH];
        for (int d = 0; d < DHH; d++) s += qs[h * DHH + d] * bfu2f(kr[d]);
        sc[h][kx] = mk ? s * 0.10783277320f : -3.0e38f;
    }
    __syncthreads();
    if (lane < HH) {
        int h = lane;
        float m = -3.0e38f;
        for (int k2 = 0; k2 < KK; k2++) m = fmaxf(m, sc[h][k2]);
        float den = 0.f;
        for (int k2 = 0; k2 < KK; k2++) {
            float e = (sc[h][k2] <= -1e37f) ? 0.f : expf(sc[h][k2] - m);
            sc[h][k2] = e;
            den += e;
        }
        float inv = (den > 0.f) ? 1.f / den : 0.f;
        for (int k2 = 0; k2 < KK; k2++) aw[h][k2] = sc[h][k2] * inv;
    }
    __syncthreads();
    bf16* orow = f1out + (size_t)node * F1S;
    for (int jj = lane; jj < DD; jj += 64) {
        int h = jj / DHH;
        float s = 0.f;
        for (int k2 = 0; k2 < KK; k2++)
            s += aw[h][k2] * bfu2f(kvls[k2][DD + jj]);
        orow[jj] = __float2bfloat16(s);
    }
    const float* src = sf + (size_t)idx[node] * DD;
    for (int c = lane; c < F1S - DD; c += 64) {     // cols 172..383: nf then 0
        float v = (c < DD) ? src[c] : 0.f;
        orow[DD + c] = __float2bfloat16(v);
    }
}

// ---------------- launch ------------------------------------------------
extern "C" void kernel_launch(void* const* d_in, const int* in_sizes, int n_in,
                              void* d_out, int out_size, void* d_ws, size_t ws_size,
                              hipStream_t stream) {
    const float* sf     = (const float*)d_in[0];
    const float* time_w = (const float*)d_in[1];
    const float* time_b = (const float*)d_in[2];
    const float* wq  = (const float*)d_in[3];
    const float* bq  = (const float*)d_in[4];
    const float* wk  = (const float*)d_in[5];
    const float* bk  = (const float*)d_in[6];
    const float* wv  = (const float*)d_in[7];
    const float* bv  = (const float*)d_in[8];
    const float* f1w = (const float*)d_in[9];
    const float* f1b = (const float*)d_in[10];
    const float* f2w = (const float*)d_in[11];
    const float* f2b = (const float*)d_in[12];
    const float* times0 = (const float*)d_in[13];
    const float* nbrt0  = (const float*)d_in[14];
    const float* times1 = (const float*)d_in[15];
    const float* nbrt1  = (const float*)d_in[16];
    const float* edge0  = (const float*)d_in[17];
    const float* edge1  = (const float*)d_in[18];
    const int* nids0 = (const int*)d_in[19];
    const int* nbr0  = (const int*)d_in[20];
    const int* nbr1  = (const int*)d_in[21];
    const int* g2l   = (const int*)d_in[22];
    const void* mask0 = d_in[23];
    const void* mask1 = d_in[24];
    float* z = (float*)d_out;

    char* wsp = (char*)d_ws;
    size_t off = 0;
    auto alloc = [&](size_t bytes) -> void* {
        void* p = wsp + off;
        off += (bytes + 255) & ~(size_t)255;
        return p;
    };
    int*   mode   = (int*)alloc(4);
    bf16*  wkvT   = (bf16*)alloc((size_t)2 * NPADR * KP * sizeof(bf16));
    float* biaskv = (float*)alloc(2 * 384 * sizeof(float));
    bf16*  wqT    = (bf16*)alloc((size_t)2 * 192 * QS * sizeof(bf16));
    float* biasq  = (float*)alloc(2 * 192 * sizeof(float));
    bf16*  f1T    = (bf16*)alloc((size_t)2 * 192 * F1S * sizeof(bf16));
    float* biasf1 = (float*)alloc(2 * 192 * sizeof(float));
    bf16*  f2T    = (bf16*)alloc((size_t)2 * 192 * HS * sizeof(bf16));
    float* biasf2 = (float*)alloc(2 * 192 * sizeof(float));
    bf16*  qin1 = (bf16*)alloc((size_t)N1C * QS * sizeof(bf16));
    bf16*  qin0 = (bf16*)alloc((size_t)N0C * QS * sizeof(bf16));
    bf16*  q1 = (bf16*)alloc((size_t)N1C * 192 * sizeof(bf16));
    bf16*  q0 = (bf16*)alloc((size_t)N0C * 192 * sizeof(bf16));
    bf16*  f1in1 = (bf16*)alloc((size_t)N1C * F1S * sizeof(bf16));
    bf16*  f1in0 = (bf16*)alloc((size_t)N0C * F1S * sizeof(bf16));
    bf16*  h1 = (bf16*)alloc((size_t)N1C * HS * sizeof(bf16));
    bf16*  h0 = (bf16*)alloc((size_t)N0C * HS * sizeof(bf16));
    bf16*  kv1 = (bf16*)alloc((size_t)M1 * KVS * sizeof(bf16));
    bf16*  kv0 = (bf16*)alloc((size_t)M0 * KVS * sizeof(bf16));
    size_t avail = (ws_size > off) ? (ws_size - off) : 0;
    size_t rows_fit = avail / ((size_t)KP * sizeof(bf16));
    long chunkRows = (long)((rows_fit / BM) * BM);
    if (chunkRows > M1) chunkRows = M1;
    if (chunkRows < BM) chunkRows = BM;
    bf16* Achunk = (bf16*)(wsp + off);

    probe_mask_kernel<<<1, 256, 0, stream>>>((const unsigned*)mask1, (N1C * KK) / 4, mode);
    {
        size_t tot = (size_t)2 * NPADR * KP;
        prep_wkvT_kernel<<<(int)((tot + 255) / 256), 256, 0, stream>>>(wk, wv, bk, bv, wkvT, biaskv);
    }
    for (int l = 0; l < 2; l++) {
        prep_wT_kernel<<<(192 * QS + 255) / 256, 256, 0, stream>>>(
            wq + (size_t)l * QIN * DD, bq + (size_t)l * DD, QIN, QS,
            wqT + (size_t)l * 192 * QS, biasq + l * 192);
        prep_wT_kernel<<<(192 * F1S + 255) / 256, 256, 0, stream>>>(
            f1w + (size_t)l * 344 * DD, f1b + (size_t)l * DD, 344, F1S,
            f1T + (size_t)l * 192 * F1S, biasf1 + l * 192);
        prep_wT_kernel<<<(192 * HS + 255) / 256, 256, 0, stream>>>(
            f2w + (size_t)l * DD * DD, f2b + (size_t)l * DD, DD, HS,
            f2T + (size_t)l * 192 * HS, biasf2 + l * 192);
    }

    // ---- layer 1 ----
    stage_qin_kernel<<<N1C / 4, 256, 0, stream>>>(sf, nbr0, time_b, qin1);
    gemm192_kernel<QS, 1, false, 0><<<N1C / BM, 256, 0, stream>>>(
        qin1, wqT + (size_t)192 * QS, biasq + 192, q1, 192, nullptr, nullptr, 0);
    for (long r0 = 0; r0 < M1; r0 += chunkRows) {
        long rows = M1 - r0 < chunkRows ? M1 - r0 : chunkRows;
        int Mt = (int)(rows / BM);
        stage_kvin_kernel<<<(int)(rows / 4), 256, 0, stream>>>(
            sf, nbr1, edge1, times1, nbrt1, mask1, mode, time_w, time_b,
            nullptr, g2l, 0, (int)r0, Achunk);
        gemm192_kernel<KP, 2, false, 0><<<Mt * 2, 256, 0, stream>>>(
            Achunk, wkvT + (size_t)NPADR * KP, biaskv + 384,
            kv1 + (size_t)r0 * KVS, KVS, nullptr, nullptr, Mt);
    }
    attn_kernel<<<N1C, 64, 0, stream>>>(q1, kv1, mask1, mode, sf, nbr0, f1in1);
    gemm192_kernel<F1S, 1, true, 0><<<N1C / BM, 256, 0, stream>>>(
        f1in1, f1T + (size_t)192 * F1S, biasf1 + 192, h1, HS, nullptr, nullptr, 0);
    gemm192_kernel<HS, 1, false, 2><<<N1C / BM, 256, 0, stream>>>(
        h1, f2T + (size_t)192 * HS, biasf2 + 192, z, DD, nbr0, g2l, 0);

    // ---- layer 0 ----
    stage_qin_kernel<<<N0C / 4, 256, 0, stream>>>(sf, nids0, time_b, qin0);
    gemm192_kernel<QS, 1, false, 0><<<N0C / BM, 256, 0, stream>>>(
        qin0, wqT, biasq, q0, 192, nullptr, nullptr, 0);
    for (long r0 = 0; r0 < M0; r0 += chunkRows) {
        long rows = M0 - r0 < chunkRows ? M0 - r0 : chunkRows;
        int Mt = (int)(rows / BM);
        stage_kvin_kernel<<<(int)(rows / 4), 256, 0, stream>>>(
            sf, nbr0, edge0, times0, nbrt0, mask0, mode, time_w, time_b,
            z, g2l, 1, (int)r0, Achunk);
        gemm192_kernel<KP, 2, false, 0><<<Mt * 2, 256, 0, stream>>>(
            Achunk, wkvT, biaskv,
            kv0 + (size_t)r0 * KVS, KVS, nullptr, nullptr, Mt);
    }
    attn_kernel<<<N0C, 64, 0, stream>>>(q0, kv0, mask0, mode, sf, nids0, f1in0);
    gemm192_kernel<F1S, 1, true, 0><<<N0C / BM, 256, 0, stream>>>(
        f1in0, f1T, biasf1, h0, HS, nullptr, nullptr, 0);
    gemm192_kernel<HS, 1, false, 2><<<N0C / BM, 256, 0, stream>>>(
        h0, f2T, biasf2, z, DD, nids0, g2l, 0);
}

// Round 5
// 679.246 us; speedup vs baseline: 1.0031x; 1.0031x over previous
//
#include <hip/hip_runtime.h>
#include <hip/hip_bf16.h>

typedef __hip_bfloat16 bf16;
typedef __attribute__((ext_vector_type(8))) short short8;
typedef __attribute__((ext_vector_type(4))) float f32x4;

#define DD    172      // D
#define EE    172      // E
#define QIN   272      // D+T
#define KK    20
#define HH    2
#define DHH   86
#define N0C   512
#define N1C   10240
#define M1    204800   // N1*K rows
#define M0    10240    // N0*K rows

// GEMM geometry
#define BM   128
#define BN   192
#define BK   64
#define KP   448       // kv_in padded K (444 -> 448)
#define QS   320       // qin padded K (272 -> 320)
#define F1S  384       // f1in padded K (344 -> 384)
#define HS   192       // h padded K (172 -> 192)
#define KVS  384       // kv row stride (k|v = 344, padded)
#define NPADR 384      // wkvT rows per layer

#define GLOAD(src, dst) __builtin_amdgcn_global_load_lds( \
    (const __attribute__((address_space(1))) unsigned int*)(src), \
    (__attribute__((address_space(3))) unsigned int*)(dst), 16, 0, 0)

__device__ __forceinline__ float bfu2f(unsigned short u) {
    return __uint_as_float(((unsigned)u) << 16);
}

// ---------------- mask dtype probe -------------------------------------
__global__ void probe_mask_kernel(const unsigned* __restrict__ m, int n_ints,
                                  int* __restrict__ mode_out) {
    __shared__ int c_other, c_float;
    if (threadIdx.x == 0) { c_other = 0; c_float = 0; }
    __syncthreads();
    int lo = 0, lf = 0;
    for (int i = threadIdx.x; i < n_ints; i += blockDim.x) {
        unsigned v = m[i];
        if (v == 0x3F800000u) lf++;
        else if (v > 1u) lo++;
    }
    if (lo) atomicAdd(&c_other, lo);
    if (lf) atomicAdd(&c_float, lf);
    __syncthreads();
    if (threadIdx.x == 0) {
        int mode = 0;
        if (c_float > 0) mode = 2;
        else if (c_other > 0) mode = 1;
        *mode_out = mode;
    }
}

__device__ __forceinline__ bool get_mask(const void* m, int mode, int idx) {
    if (mode == 1) return ((const unsigned char*)m)[idx] != 0;
    if (mode == 2) return ((const float*)m)[idx] != 0.0f;
    return ((const int*)m)[idx] != 0;
}

// ---------------- weight prep: wkvT[l][n][k] bf16 + fused bias(384) -----
__global__ void prep_wkvT_kernel(const float* __restrict__ wk, const float* __restrict__ wv,
                                 const float* __restrict__ bk, const float* __restrict__ bv,
                                 bf16* __restrict__ wkvT, float* __restrict__ biaskv) {
    size_t i = (size_t)blockIdx.x * blockDim.x + threadIdx.x;
    size_t tot = (size_t)2 * NPADR * KP;
    if (i >= tot) return;
    int l = (int)(i / ((size_t)NPADR * KP));
    int rem = (int)(i % ((size_t)NPADR * KP));
    int k = rem / NPADR;
    int n = rem % NPADR;
    float v = 0.f;
    if (k < 444) {
        if (n < DD)          v = wk[((size_t)l * 444 + k) * DD + n];
        else if (n < 2 * DD) v = wv[((size_t)l * 444 + k) * DD + (n - DD)];
    }
    wkvT[((size_t)l * NPADR + n) * KP + k] = __float2bfloat16(v);
    if (i < 2 * 384) {
        int nn = (int)(i % 384), ll = (int)(i / 384);
        biaskv[i] = nn < DD ? bk[ll * DD + nn] : (nn < 2 * DD ? bv[ll * DD + nn - DD] : 0.f);
    }
}

// ---------------- generic weight transpose: W[K][172] -> dstT[192][KPdst]
__global__ void prep_wT_kernel(const float* __restrict__ W, const float* __restrict__ b,
                               int K, int KPdst,
                               bf16* __restrict__ dstT, float* __restrict__ biasdst) {
    int i = blockIdx.x * blockDim.x + threadIdx.x;
    int tot = 192 * KPdst;
    if (i < tot) {
        int n = i / KPdst, k = i % KPdst;
        float v = (n < DD && k < K) ? W[(size_t)k * DD + n] : 0.f;
        dstT[(size_t)n * KPdst + k] = __float2bfloat16(v);
    }
    if (i < 192) biasdst[i] = (i < DD) ? b[i] : 0.f;
}

// ---------------- kv_in staging: [nbr_feat | edge | cos(dt*w+b) | 0pad] --
// 16B-vectorized: lane u < 56 handles cols [8u, 8u+8)
__global__ __launch_bounds__(256) void stage_kvin_kernel(
    const float* __restrict__ sf, const int* __restrict__ nbrs,
    const float* __restrict__ edge, const float* __restrict__ times,
    const float* __restrict__ nbrt,
    const void* __restrict__ mask, const int* __restrict__ mode_p,
    const float* __restrict__ time_w, const float* __restrict__ time_b,
    const float* __restrict__ zbuf, const int* __restrict__ g2l, int use_z,
    int row0, bf16* __restrict__ out) {
    int wave = threadIdx.x >> 6, lane = threadIdx.x & 63;
    int lrow = blockIdx.x * 4 + wave;
    int row = row0 + lrow;
    int mode = *mode_p;
    int g = nbrs[row];
    bool mk = get_mask(mask, mode, row);
    float dt = mk ? (times[row / KK] - nbrt[row]) : 0.f;
    const float* src = (use_z && mk) ? (zbuf + (size_t)g2l[g] * DD)
                                     : (sf + (size_t)g * DD);
    const float* erow = edge + (size_t)row * EE;
    bf16* orow = out + (size_t)lrow * KP;
    if (lane < 56) {
        int c0 = lane * 8;
        union { bf16 h[8]; short8 s; } u;
#pragma unroll
        for (int e = 0; e < 8; ++e) {
            int col = c0 + e;
            float v;
            if (col < DD)           v = src[col];
            else if (col < DD + EE) v = erow[col - DD];
            else if (col < 444)     { int t = col - DD - EE; v = cosf(dt * time_w[t] + time_b[t]); }
            else                    v = 0.f;
            u.h[e] = __float2bfloat16(v);
        }
        *(short8*)(orow + c0) = u.s;
    }
}

// ---------------- q_in staging: [feat | cos(time_b) | 0pad] -------------
__global__ __launch_bounds__(256) void stage_qin_kernel(
    const float* __restrict__ sf, const int* __restrict__ idx,
    const float* __restrict__ time_b, bf16* __restrict__ out) {
    int wave = threadIdx.x >> 6, lane = threadIdx.x & 63;
    int row = blockIdx.x * 4 + wave;
    const float* src = sf + (size_t)idx[row] * DD;
    bf16* orow = out + (size_t)row * QS;
    if (lane < 40) {
        int c0 = lane * 8;
        union { bf16 h[8]; short8 s; } u;
#pragma unroll
        for (int e = 0; e < 8; ++e) {
            int col = c0 + e;
            float v;
            if (col < DD)       v = src[col];
            else if (col < QIN) v = cosf(time_b[col - DD]);
            else                v = 0.f;
            u.h[e] = __float2bfloat16(v);
        }
        *(short8*)(orow + c0) = u.s;
    }
}

// ---------------- 192-col MFMA GEMM -------------------------------------
// 128x192 tile, 4 waves in 2M x 2N, per wave 64x96 (acc 4x6 frags).
// LDS = As 16K + Bs 24K = 40KB (4 blocks/CU). Scalar epilogue stores.
// OMODE 0: bf16 dense out (stride ostride). OMODE 2: fp32 scatter via g2l[idx].
template<int KP_, int NT, bool RELU, int OMODE>
__global__ __launch_bounds__(256) void gemm192_kernel(
    const bf16* __restrict__ A, const bf16* __restrict__ BT,
    const float* __restrict__ bias, void* __restrict__ outp, int ostride,
    const int* __restrict__ idx, const int* __restrict__ g2l, int Mtiles) {
    __shared__ __align__(16) char smem[40960];   // As 16K | Bs 24K
    int tid = threadIdx.x;
    int lane = tid & 63, wave = tid >> 6;
    int ml = lane & 15, kg = lane >> 4;
    int wm = wave >> 1, wn = wave & 1;
    int bid = blockIdx.x;
    int mt = (NT == 2) ? (bid % Mtiles) : bid;
    int nt = (NT == 2) ? (bid / Mtiles) : 0;
    int m0 = mt * BM, n0 = nt * BN;

    f32x4 acc[4][6];
#pragma unroll
    for (int mg = 0; mg < 4; ++mg)
#pragma unroll
        for (int fn = 0; fn < 6; ++fn)
            acc[mg][fn] = (f32x4){0.f, 0.f, 0.f, 0.f};

    for (int kk = 0; kk < KP_; kk += BK) {
        // stage A: 128 rows x 8 slots = 1024 chunks; linear LDS dest, pre-swizzled src
#pragma unroll
        for (int it = 0; it < 4; ++it) {
            int c = it * 256 + tid;
            int row = c >> 3, slot = c & 7;
            int sslot = slot ^ (row & 7);
            const bf16* src = A + (size_t)(m0 + row) * KP_ + kk + sslot * 8;
            GLOAD(src, smem + (size_t)(it * 256 + wave * 64) * 16);
        }
        // stage B: 192 rows x 8 slots = 1536 chunks
#pragma unroll
        for (int it = 0; it < 6; ++it) {
            int c = it * 256 + tid;
            int row = c >> 3, slot = c & 7;
            int sslot = slot ^ (row & 7);
            const bf16* src = BT + (size_t)(n0 + row) * KP_ + kk + sslot * 8;
            GLOAD(src, smem + 16384 + (size_t)(it * 256 + wave * 64) * 16);
        }
        __syncthreads();
#pragma unroll
        for (int half = 0; half < 2; ++half) {
            int kc = kg + half * 4;
            short8 a[4], b[6];
#pragma unroll
            for (int mg = 0; mg < 4; ++mg) {
                int r = wm * 64 + mg * 16 + ml;
                a[mg] = *(const short8*)(smem + r * 128 + ((kc ^ (r & 7)) << 4));
            }
#pragma unroll
            for (int fn = 0; fn < 6; ++fn) {
                int r = wn * 96 + fn * 16 + ml;
                b[fn] = *(const short8*)(smem + 16384 + r * 128 + ((kc ^ (r & 7)) << 4));
            }
#pragma unroll
            for (int mg = 0; mg < 4; ++mg)
#pragma unroll
                for (int fn = 0; fn < 6; ++fn)
                    acc[mg][fn] = __builtin_amdgcn_mfma_f32_16x16x32_bf16(a[mg], b[fn], acc[mg][fn], 0, 0, 0);
        }
        __syncthreads();
    }

    if (OMODE == 0) {
#pragma unroll
        for (int fn = 0; fn < 6; ++fn) {
            int col = wn * 96 + fn * 16 + ml;
            float bb = bias[n0 + col];
#pragma unroll
            for (int mg = 0; mg < 4; ++mg)
#pragma unroll
                for (int r4 = 0; r4 < 4; ++r4) {
                    int row = m0 + wm * 64 + mg * 16 + kg * 4 + r4;
                    float v = acc[mg][fn][r4] + bb;
                    if (RELU) v = fmaxf(v, 0.f);
                    ((bf16*)outp)[(size_t)row * ostride + n0 + col] = __float2bfloat16(v);
                }
        }
    } else {
        // fp32 scatter (FFN2 -> z)
#pragma unroll
        for (int fn = 0; fn < 6; ++fn) {
            int col = wn * 96 + fn * 16 + ml;
            if (col < DD) {
                float bb = bias[col];
#pragma unroll
                for (int mg = 0; mg < 4; ++mg)
#pragma unroll
                    for (int r4 = 0; r4 < 4; ++r4) {
                        int row = m0 + wm * 64 + mg * 16 + kg * 4 + r4;
                        float v = acc[mg][fn][r4] + bb;
                        if (RELU) v = fmaxf(v, 0.f);
                        int zr = g2l[idx[row]];
                        ((float*)outp)[(size_t)zr * DD + col] = v;
                    }
            }
        }
    }
}

// ---------------- attention over K=20 neighbors -------------------------
// kv row stride 384; q bf16 stride 192. Writes o + gathered nf into f1in[row][F1S].
#define ASTR 392
__global__ __launch_bounds__(64) void attn_kernel(
    const bf16* __restrict__ q, const bf16* __restrict__ kv,
    const void* __restrict__ mask, const int* __restrict__ mode_p,
    const float* __restrict__ sf, const int* __restrict__ idx,
    bf16* __restrict__ f1out) {
    int node = blockIdx.x;
    int lane = threadIdx.x;
    __shared__ unsigned short kvls[KK][ASTR];
    __shared__ float qs[DD];
    __shared__ float sc[HH][KK];
    __shared__ float aw[HH][KK];
    int mode = *mode_p;
    const unsigned short* kvg = (const unsigned short*)(kv + (size_t)node * KK * KVS);
    for (int c = lane; c < 960; c += 64) {          // 20*384/8 chunks, contiguous
        int r = c / 48, cc = c % 48;
        *(short8*)&kvls[r][cc * 8] = *(const short8*)(kvg + (size_t)c * 8);
    }
    const unsigned short* qrow = (const unsigned short*)q + (size_t)node * 192;
    for (int i = lane; i < DD; i += 64) qs[i] = bfu2f(qrow[i]);
    __syncthreads();
    if (lane < HH * KK) {
        int h = lane / KK, kx = lane % KK;
        bool mk = get_mask(mask, mode, node * KK + kx);
        float s = 0.f;
        const unsigned short* kr = &kvls[kx][h * DHH];
        for (int d = 0; d < DHH; d++) s += qs[h * DHH + d] * bfu2f(kr[d]);
        sc[h][kx] = mk ? s * 0.10783277320f : -3.0e38f;
    }
    __syncthreads();
    if (lane < HH) {
        int h = lane;
        float m = -3.0e38f;
        for (int k2 = 0; k2 < KK; k2++) m = fmaxf(m, sc[h][k2]);
        float den = 0.f;
        for (int k2 = 0; k2 < KK; k2++) {
            float e = (sc[h][k2] <= -1e37f) ? 0.f : expf(sc[h][k2] - m);
            sc[h][k2] = e;
            den += e;
        }
        float inv = (den > 0.f) ? 1.f / den : 0.f;
        for (int k2 = 0; k2 < KK; k2++) aw[h][k2] = sc[h][k2] * inv;
    }
    __syncthreads();
    bf16* orow = f1out + (size_t)node * F1S;
    for (int jj = lane; jj < DD; jj += 64) {
        int h = jj / DHH;
        float s = 0.f;
        for (int k2 = 0; k2 < KK; k2++)
            s += aw[h][k2] * bfu2f(kvls[k2][DD + jj]);
        orow[jj] = __float2bfloat16(s);
    }
    const float* src = sf + (size_t)idx[node] * DD;
    for (int c = lane; c < F1S - DD; c += 64) {     // cols 172..383: nf then 0
        float v = (c < DD) ? src[c] : 0.f;
        orow[DD + c] = __float2bfloat16(v);
    }
}

// ---------------- launch ------------------------------------------------
extern "C" void kernel_launch(void* const* d_in, const int* in_sizes, int n_in,
                              void* d_out, int out_size, void* d_ws, size_t ws_size,
                              hipStream_t stream) {
    const float* sf     = (const float*)d_in[0];
    const float* time_w = (const float*)d_in[1];
    const float* time_b = (const float*)d_in[2];
    const float* wq  = (const float*)d_in[3];
    const float* bq  = (const float*)d_in[4];
    const float* wk  = (const float*)d_in[5];
    const float* bk  = (const float*)d_in[6];
    const float* wv  = (const float*)d_in[7];
    const float* bv  = (const float*)d_in[8];
    const float* f1w = (const float*)d_in[9];
    const float* f1b = (const float*)d_in[10];
    const float* f2w = (const float*)d_in[11];
    const float* f2b = (const float*)d_in[12];
    const float* times0 = (const float*)d_in[13];
    const float* nbrt0  = (const float*)d_in[14];
    const float* times1 = (const float*)d_in[15];
    const float* nbrt1  = (const float*)d_in[16];
    const float* edge0  = (const float*)d_in[17];
    const float* edge1  = (const float*)d_in[18];
    const int* nids0 = (const int*)d_in[19];
    const int* nbr0  = (const int*)d_in[20];
    const int* nbr1  = (const int*)d_in[21];
    const int* g2l   = (const int*)d_in[22];
    const void* mask0 = d_in[23];
    const void* mask1 = d_in[24];
    float* z = (float*)d_out;

    char* wsp = (char*)d_ws;
    size_t off = 0;
    auto alloc = [&](size_t bytes) -> void* {
        void* p = wsp + off;
        off += (bytes + 255) & ~(size_t)255;
        return p;
    };
    int*   mode   = (int*)alloc(4);
    bf16*  wkvT   = (bf16*)alloc((size_t)2 * NPADR * KP * sizeof(bf16));
    float* biaskv = (float*)alloc(2 * 384 * sizeof(float));
    bf16*  wqT    = (bf16*)alloc((size_t)2 * 192 * QS * sizeof(bf16));
    float* biasq  = (float*)alloc(2 * 192 * sizeof(float));
    bf16*  f1T    = (bf16*)alloc((size_t)2 * 192 * F1S * sizeof(bf16));
    float* biasf1 = (float*)alloc(2 * 192 * sizeof(float));
    bf16*  f2T    = (bf16*)alloc((size_t)2 * 192 * HS * sizeof(bf16));
    float* biasf2 = (float*)alloc(2 * 192 * sizeof(float));
    bf16*  qin1 = (bf16*)alloc((size_t)N1C * QS * sizeof(bf16));
    bf16*  qin0 = (bf16*)alloc((size_t)N0C * QS * sizeof(bf16));
    bf16*  q1 = (bf16*)alloc((size_t)N1C * 192 * sizeof(bf16));
    bf16*  q0 = (bf16*)alloc((size_t)N0C * 192 * sizeof(bf16));
    bf16*  f1in1 = (bf16*)alloc((size_t)N1C * F1S * sizeof(bf16));
    bf16*  f1in0 = (bf16*)alloc((size_t)N0C * F1S * sizeof(bf16));
    bf16*  h1 = (bf16*)alloc((size_t)N1C * HS * sizeof(bf16));
    bf16*  h0 = (bf16*)alloc((size_t)N0C * HS * sizeof(bf16));
    bf16*  kv1 = (bf16*)alloc((size_t)M1 * KVS * sizeof(bf16));
    bf16*  kv0 = (bf16*)alloc((size_t)M0 * KVS * sizeof(bf16));
    size_t avail = (ws_size > off) ? (ws_size - off) : 0;
    size_t rows_fit = avail / ((size_t)KP * sizeof(bf16));
    long chunkRows = (long)((rows_fit / BM) * BM);
    if (chunkRows > M1) chunkRows = M1;
    if (chunkRows < BM) chunkRows = BM;
    bf16* Achunk = (bf16*)(wsp + off);

    probe_mask_kernel<<<1, 256, 0, stream>>>((const unsigned*)mask1, (N1C * KK) / 4, mode);
    {
        size_t tot = (size_t)2 * NPADR * KP;
        prep_wkvT_kernel<<<(int)((tot + 255) / 256), 256, 0, stream>>>(wk, wv, bk, bv, wkvT, biaskv);
    }
    for (int l = 0; l < 2; l++) {
        prep_wT_kernel<<<(192 * QS + 255) / 256, 256, 0, stream>>>(
            wq + (size_t)l * QIN * DD, bq + (size_t)l * DD, QIN, QS,
            wqT + (size_t)l * 192 * QS, biasq + l * 192);
        prep_wT_kernel<<<(192 * F1S + 255) / 256, 256, 0, stream>>>(
            f1w + (size_t)l * 344 * DD, f1b + (size_t)l * DD, 344, F1S,
            f1T + (size_t)l * 192 * F1S, biasf1 + l * 192);
        prep_wT_kernel<<<(192 * HS + 255) / 256, 256, 0, stream>>>(
            f2w + (size_t)l * DD * DD, f2b + (size_t)l * DD, DD, HS,
            f2T + (size_t)l * 192 * HS, biasf2 + l * 192);
    }

    // ---- layer 1 ----
    stage_qin_kernel<<<N1C / 4, 256, 0, stream>>>(sf, nbr0, time_b, qin1);
    gemm192_kernel<QS, 1, false, 0><<<N1C / BM, 256, 0, stream>>>(
        qin1, wqT + (size_t)192 * QS, biasq + 192, q1, 192, nullptr, nullptr, 0);
    for (long r0 = 0; r0 < M1; r0 += chunkRows) {
        long rows = M1 - r0 < chunkRows ? M1 - r0 : chunkRows;
        int Mt = (int)(rows / BM);
        stage_kvin_kernel<<<(int)(rows / 4), 256, 0, stream>>>(
            sf, nbr1, edge1, times1, nbrt1, mask1, mode, time_w, time_b,
            nullptr, g2l, 0, (int)r0, Achunk);
        gemm192_kernel<KP, 2, false, 0><<<Mt * 2, 256, 0, stream>>>(
            Achunk, wkvT + (size_t)NPADR * KP, biaskv + 384,
            kv1 + (size_t)r0 * KVS, KVS, nullptr, nullptr, Mt);
    }
    attn_kernel<<<N1C, 64, 0, stream>>>(q1, kv1, mask1, mode, sf, nbr0, f1in1);
    gemm192_kernel<F1S, 1, true, 0><<<N1C / BM, 256, 0, stream>>>(
        f1in1, f1T + (size_t)192 * F1S, biasf1 + 192, h1, HS, nullptr, nullptr, 0);
    gemm192_kernel<HS, 1, false, 2><<<N1C / BM, 256, 0, stream>>>(
        h1, f2T + (size_t)192 * HS, biasf2 + 192, z, DD, nbr0, g2l, 0);

    // ---- layer 0 ----
    stage_qin_kernel<<<N0C / 4, 256, 0, stream>>>(sf, nids0, time_b, qin0);
    gemm192_kernel<QS, 1, false, 0><<<N0C / BM, 256, 0, stream>>>(
        qin0, wqT, biasq, q0, 192, nullptr, nullptr, 0);
    for (long r0 = 0; r0 < M0; r0 += chunkRows) {
        long rows = M0 - r0 < chunkRows ? M0 - r0 : chunkRows;
        int Mt = (int)(rows / BM);
        stage_kvin_kernel<<<(int)(rows / 4), 256, 0, stream>>>(
            sf, nbr0, edge0, times0, nbrt0, mask0, mode, time_w, time_b,
            z, g2l, 1, (int)r0, Achunk);
        gemm192_kernel<KP, 2, false, 0><<<Mt * 2, 256, 0, stream>>>(
            Achunk, wkvT, biaskv,
            kv0 + (size_t)r0 * KVS, KVS, nullptr, nullptr, Mt);
    }
    attn_kernel<<<N0C, 64, 0, stream>>>(q0, kv0, mask0, mode, sf, nids0, f1in0);
    gemm192_kernel<F1S, 1, true, 0><<<N0C / BM, 256, 0, stream>>>(
        f1in0, f1T, biasf1, h0, HS, nullptr, nullptr, 0);
    gemm192_kernel<HS, 1, false, 2><<<N0C / BM, 256, 0, stream>>>(
        h0, f2T, biasf2, z, DD, nids0, g2l, 0);
}